// Round 18
// baseline (65.784 us; speedup 1.0000x reference)
//
#include <hip/hip_runtime.h>
#include <math.h>

#define NTX_EPS 1e-8f

typedef __fp16 half8 __attribute__((ext_vector_type(8)));
typedef __fp16 half2v __attribute__((ext_vector_type(2)));
typedef float f32x4 __attribute__((ext_vector_type(4)));

union H8 { half8 v8; half2v v2[4]; };

__device__ __forceinline__ half8 pack8(const float4& a, const float4& b) {
    H8 u;
    u.v2[0] = __builtin_amdgcn_cvt_pkrtz(a.x, a.y);
    u.v2[1] = __builtin_amdgcn_cvt_pkrtz(a.z, a.w);
    u.v2[2] = __builtin_amdgcn_cvt_pkrtz(b.x, b.y);
    u.v2[3] = __builtin_amdgcn_cvt_pkrtz(b.z, b.w);
    return u.v8;
}

// Opaque async load (R12-proven): one global_load_dwordx4 per call; compiler
// cannot recycle destinations into a serialized chain. NO nt: R17 showed nt
// bypasses L3 residency across graph replays (wall 52.3 -> 58.5 regression).
__device__ __forceinline__ float4 gl4(const float* p) {
    float4 d;
    asm volatile("global_load_dwordx4 %0, %1, off" : "=v"(d) : "v"(p) : "memory");
    return d;
}
#define WAITVM(n) do { asm volatile("s_waitcnt vmcnt(" #n ")" ::: "memory"); \
                       __builtin_amdgcn_sched_barrier(0); } while (0)

#define ISSUE(g, s) \
    float4 g##T0 = gl4(tsrc + (s) * 32); \
    float4 g##T1 = gl4(tsrc + (s) * 32 + 4); \
    float4 g##R0 = gl4(rsrc + (s) * 32); \
    float4 g##R1 = gl4(rsrc + (s) * 32 + 4);

#define COMPUTE(g) { \
    half8 tf = pack8(g##T0, g##T1); \
    half8 rf = pack8(g##R0, g##R1); \
    acc_tt = __builtin_amdgcn_mfma_f32_16x16x32_f16(tf, tf, acc_tt, 0, 0, 0); \
    acc_tr = __builtin_amdgcn_mfma_f32_16x16x32_f16(tf, rf, acc_tr, 0, 0, 0); \
    acc_rr = __builtin_amdgcn_mfma_f32_16x16x32_f16(rf, rf, acc_rr, 0, 0, 0); }

// Reduce 16 wave-partial Grams in LDS and compute one level's loss.
// Returns the loss (valid at t==0 only). Safe to call twice back-to-back.
__device__ __forceinline__ float reduce_loss(
    float (*red)[528], float (*Gs)[33], float* rn2, float* tnS, float* rnS,
    int t, int w, int row, int kg,
    const f32x4& acc_tt, const f32x4& acc_tr, const f32x4& acc_rr)
{
    const int m = row;
#pragma unroll
    for (int r = 0; r < 4; ++r) {
        const int n = kg * 4 + r;
        red[w][n * 16 + m]       = acc_tt[r];
        red[w][256 + n * 16 + m] = acc_tr[r];
    }
    if ((m >> 2) == kg) red[w][512 + m] = acc_rr[m & 3];
    __syncthreads();

    if (t < 256) {
        float stt = 0.f, str = 0.f;
#pragma unroll
        for (int p = 0; p < 16; ++p) {
            stt += red[p][t];
            str += red[p][256 + t];
        }
        Gs[t >> 4][t & 15]        = stt;
        Gs[t >> 4][16 + (t & 15)] = str;
    } else if (t < 272) {
        const int e = t - 256;
        float s = 0.f;
#pragma unroll
        for (int p = 0; p < 16; ++p) s += red[p][512 + e];
        rn2[e] = s;
    }
    __syncthreads();

    if (t < 16) {
        tnS[t] = fmaxf(sqrtf(Gs[t][t]), NTX_EPS);
        rnS[t] = fmaxf(sqrtf(rn2[t]), NTX_EPS);
    }
    __syncthreads();

    float loss = 0.f;
    if (t < 16) {
        const int n = t;
        const float itn = 2.0f / tnS[n];         // includes 1/temperature
        float lg[32];
#pragma unroll
        for (int j = 0; j < 16; ++j)
            lg[j] = Gs[n][16 + j] * itn / rnS[j];      // s_tr row
#pragma unroll
        for (int k = 0; k < 16; ++k)
            lg[16 + k] = Gs[n][k] * itn / tnS[k];      // s_tt row
        const float pos = lg[n];
        float mx = -3.4e38f;
#pragma unroll
        for (int j = 0; j < 32; ++j)
            mx = (j == 16 + n) ? mx : fmaxf(mx, lg[j]);    // exclude tt diag
        float sm = 0.f;
#pragma unroll
        for (int j = 0; j < 32; ++j)
            sm += (j == 16 + n) ? 0.f : expf(lg[j] - mx);
        loss = logf(sm) + mx - pos;
    }
    loss += __shfl_xor(loss, 1, 64);
    loss += __shfl_xor(loss, 2, 64);
    loss += __shfl_xor(loss, 4, 64);
    loss += __shfl_xor(loss, 8, 64);
    return loss;                                  // valid at t==0
}

// SINGLE kernel: 512 blocks x 1024 threads (16 waves) = exactly 2 blocks/CU.
//   bid <  grid/2 : type 0 = level 0 of batch bid           (512 KB)
//   bid >= grid/2 : type 1 = levels 1+2 of batch bid-grid/2 (384 KB)
// Half-split decorrelates type from the XCD round-robin (bid%8): each XCD
// gets 32 heavy + 32 light (R17: profiled 91 -> 64 us). R16's type=bid&1
// aliased with XCD parity (33% per-XCD imbalance). Loads are plain (cached):
// nt cost 6us of wall by defeating L3 residency across graph replays (R17).
// Per wave: verified R12 ISA load-ring (lane l feeds Gram row l&15, k-group
// l>>4; one half8 is both A and B; mfma(t,t)/(t,r)/(r,r); C/D col=l&15,
// row=kg*4+r). In-block 16-wave LDS reduce + loss; one atomicAdd per block.
// No fences (R14 lesson). VGPR <= 64 (8 waves/SIMD): R15-R17 builds = 52.
__global__ __launch_bounds__(1024)
void ntxent_one(const float* __restrict__ ts0, const float* __restrict__ rs0,
                const float* __restrict__ ts1, const float* __restrict__ rs1,
                const float* __restrict__ ts2, const float* __restrict__ rs2,
                float* __restrict__ out)
{
    __shared__ float red[16][528];
    __shared__ float Gs[16][33];
    __shared__ float rn2[16], tnS[16], rnS[16];

    const int bid  = blockIdx.x;
    const int half = gridDim.x >> 1;
    const int type = (bid >= half) ? 1 : 0;
    const int b    = type ? (bid - half) : bid;

    const int t   = threadIdx.x;
    const int w   = t >> 6;          // wave 0..15
    const int l   = t & 63;
    const int row = l & 15;
    const int kg  = l >> 4;

    float lossTot = 0.f;             // valid at t==0

    if (type == 0) {
        // ---- level 0: D=4096, 256 floats/wave, 8 K-steps, depth-20 ring ----
        const int D = 4096;
        const size_t base = (size_t)b * 16 * D + (size_t)row * D
                          + (size_t)w * 256 + (size_t)kg * 8;
        const float* tsrc = ts0 + base;
        const float* rsrc = rs0 + base;
        f32x4 acc_tt = {0.f, 0.f, 0.f, 0.f};
        f32x4 acc_tr = {0.f, 0.f, 0.f, 0.f};
        f32x4 acc_rr = {0.f, 0.f, 0.f, 0.f};
        ISSUE(g0, 0) ISSUE(g1, 1) ISSUE(g2, 2) ISSUE(g3, 3)
        ISSUE(g4, 4) WAITVM(16); COMPUTE(g0)
        ISSUE(g5, 5) WAITVM(16); COMPUTE(g1)
        ISSUE(g6, 6) WAITVM(16); COMPUTE(g2)
        ISSUE(g7, 7) WAITVM(16); COMPUTE(g3)
        WAITVM(12);  COMPUTE(g4)
        WAITVM(8);   COMPUTE(g5)
        WAITVM(4);   COMPUTE(g6)
        WAITVM(0);   COMPUTE(g7)
        lossTot = reduce_loss(red, Gs, rn2, tnS, rnS, t, w, row, kg,
                              acc_tt, acc_tr, acc_rr);
    } else {
        // ---- level 1: D=2048, 128 floats/wave, 4 K-steps ----
        {
            const int D = 2048;
            const size_t base = (size_t)b * 16 * D + (size_t)row * D
                              + (size_t)w * 128 + (size_t)kg * 8;
            const float* tsrc = ts1 + base;
            const float* rsrc = rs1 + base;
            f32x4 acc_tt = {0.f, 0.f, 0.f, 0.f};
            f32x4 acc_tr = {0.f, 0.f, 0.f, 0.f};
            f32x4 acc_rr = {0.f, 0.f, 0.f, 0.f};
            ISSUE(g0, 0) ISSUE(g1, 1) ISSUE(g2, 2) ISSUE(g3, 3)
            WAITVM(12);  COMPUTE(g0)
            WAITVM(8);   COMPUTE(g1)
            WAITVM(4);   COMPUTE(g2)
            WAITVM(0);   COMPUTE(g3)
            lossTot = reduce_loss(red, Gs, rn2, tnS, rnS, t, w, row, kg,
                                  acc_tt, acc_tr, acc_rr);
        }
        // ---- level 2: D=1024, 64 floats/wave, 2 K-steps ----
        {
            const int D = 1024;
            const size_t base = (size_t)b * 16 * D + (size_t)row * D
                              + (size_t)w * 64 + (size_t)kg * 8;
            const float* tsrc = ts2 + base;
            const float* rsrc = rs2 + base;
            f32x4 acc_tt = {0.f, 0.f, 0.f, 0.f};
            f32x4 acc_tr = {0.f, 0.f, 0.f, 0.f};
            f32x4 acc_rr = {0.f, 0.f, 0.f, 0.f};
            ISSUE(g0, 0) ISSUE(g1, 1)
            WAITVM(4);   COMPUTE(g0)
            WAITVM(0);   COMPUTE(g1)
            lossTot += reduce_loss(red, Gs, rn2, tnS, rnS, t, w, row, kg,
                                   acc_tt, acc_tr, acc_rr);
        }
    }

    if (t == 0) atomicAdd(out, lossTot * (1.0f / 512.0f));
}

extern "C" void kernel_launch(void* const* d_in, const int* in_sizes, int n_in,
                              void* d_out, int out_size, void* d_ws, size_t ws_size,
                              hipStream_t stream) {
    const float* ts0 = (const float*)d_in[0];
    const float* rs0 = (const float*)d_in[1];
    const float* ts1 = (const float*)d_in[2];
    const float* rs1 = (const float*)d_in[3];
    const float* ts2 = (const float*)d_in[4];
    const float* rs2 = (const float*)d_in[5];
    float* out = (float*)d_out;

    hipMemsetAsync(out, 0, sizeof(float), stream);

    const int B = in_sizes[0] / (16 * 4096);   // 256
    hipLaunchKernelGGL(ntxent_one, dim3(B * 2), dim3(1024), 0, stream,
                       ts0, rs0, ts1, rs1, ts2, rs2, out);
}

// Round 19
// 60.743 us; speedup vs baseline: 1.0830x; 1.0830x over previous
//
#include <hip/hip_runtime.h>
#include <math.h>

#define NTX_EPS 1e-8f

typedef __fp16 half8 __attribute__((ext_vector_type(8)));
typedef __fp16 half2v __attribute__((ext_vector_type(2)));
typedef float f32x4 __attribute__((ext_vector_type(4)));

union H8 { half8 v8; half2v v2[4]; };

__device__ __forceinline__ half8 pack8(const float4& a, const float4& b) {
    H8 u;
    u.v2[0] = __builtin_amdgcn_cvt_pkrtz(a.x, a.y);
    u.v2[1] = __builtin_amdgcn_cvt_pkrtz(a.z, a.w);
    u.v2[2] = __builtin_amdgcn_cvt_pkrtz(b.x, b.y);
    u.v2[3] = __builtin_amdgcn_cvt_pkrtz(b.z, b.w);
    return u.v8;
}

// Opaque async load (R12-proven) with nt: skip L2 allocation for the
// read-once stream (memory-side L3 still captures it). R17/R18 2x2 showed
// nt helps BOTH wall and profile within a fixed layout; the R17 wall
// regression was the half-split layout, not nt.
__device__ __forceinline__ float4 gl4(const float* p) {
    float4 d;
    asm volatile("global_load_dwordx4 %0, %1, off nt" : "=v"(d) : "v"(p) : "memory");
    return d;
}
#define WAITVM(n) do { asm volatile("s_waitcnt vmcnt(" #n ")" ::: "memory"); \
                       __builtin_amdgcn_sched_barrier(0); } while (0)

#define ISSUE(g, s) \
    float4 g##T0 = gl4(tsrc + (s) * 32); \
    float4 g##T1 = gl4(tsrc + (s) * 32 + 4); \
    float4 g##R0 = gl4(rsrc + (s) * 32); \
    float4 g##R1 = gl4(rsrc + (s) * 32 + 4);

#define COMPUTE(g) { \
    half8 tf = pack8(g##T0, g##T1); \
    half8 rf = pack8(g##R0, g##R1); \
    acc_tt = __builtin_amdgcn_mfma_f32_16x16x32_f16(tf, tf, acc_tt, 0, 0, 0); \
    acc_tr = __builtin_amdgcn_mfma_f32_16x16x32_f16(tf, rf, acc_tr, 0, 0, 0); \
    acc_rr = __builtin_amdgcn_mfma_f32_16x16x32_f16(rf, rf, acc_rr, 0, 0, 0); }

// Reduce 16 wave-partial Grams in LDS and compute one level's loss.
// Returns the loss (valid at t==0 only). Safe to call twice back-to-back.
__device__ __forceinline__ float reduce_loss(
    float (*red)[528], float (*Gs)[33], float* rn2, float* tnS, float* rnS,
    int t, int w, int row, int kg,
    const f32x4& acc_tt, const f32x4& acc_tr, const f32x4& acc_rr)
{
    const int m = row;
#pragma unroll
    for (int r = 0; r < 4; ++r) {
        const int n = kg * 4 + r;
        red[w][n * 16 + m]       = acc_tt[r];
        red[w][256 + n * 16 + m] = acc_tr[r];
    }
    if ((m >> 2) == kg) red[w][512 + m] = acc_rr[m & 3];
    __syncthreads();

    if (t < 256) {
        float stt = 0.f, str = 0.f;
#pragma unroll
        for (int p = 0; p < 16; ++p) {
            stt += red[p][t];
            str += red[p][256 + t];
        }
        Gs[t >> 4][t & 15]        = stt;
        Gs[t >> 4][16 + (t & 15)] = str;
    } else if (t < 272) {
        const int e = t - 256;
        float s = 0.f;
#pragma unroll
        for (int p = 0; p < 16; ++p) s += red[p][512 + e];
        rn2[e] = s;
    }
    __syncthreads();

    if (t < 16) {
        tnS[t] = fmaxf(sqrtf(Gs[t][t]), NTX_EPS);
        rnS[t] = fmaxf(sqrtf(rn2[t]), NTX_EPS);
    }
    __syncthreads();

    float loss = 0.f;
    if (t < 16) {
        const int n = t;
        const float itn = 2.0f / tnS[n];         // includes 1/temperature
        float lg[32];
#pragma unroll
        for (int j = 0; j < 16; ++j)
            lg[j] = Gs[n][16 + j] * itn / rnS[j];      // s_tr row
#pragma unroll
        for (int k = 0; k < 16; ++k)
            lg[16 + k] = Gs[n][k] * itn / tnS[k];      // s_tt row
        const float pos = lg[n];
        float mx = -3.4e38f;
#pragma unroll
        for (int j = 0; j < 32; ++j)
            mx = (j == 16 + n) ? mx : fmaxf(mx, lg[j]);    // exclude tt diag
        float sm = 0.f;
#pragma unroll
        for (int j = 0; j < 32; ++j)
            sm += (j == 16 + n) ? 0.f : expf(lg[j] - mx);
        loss = logf(sm) + mx - pos;
    }
    loss += __shfl_xor(loss, 1, 64);
    loss += __shfl_xor(loss, 2, 64);
    loss += __shfl_xor(loss, 4, 64);
    loss += __shfl_xor(loss, 8, 64);
    return loss;                                  // valid at t==0
}

// SINGLE kernel: 512 blocks x 1024 threads (16 waves) = exactly 2 blocks/CU.
// Block (b = bid>>1, type = bid&1)  [R16 layout — best wall 52.3us]:
//   type 0: level 0 of batch b        (512 KB)
//   type 1: levels 1+2 of batch b     (384 KB)
// R18 2x2 decomposition: this layout (homogeneous stream type per XCD,
// same-batch pairs adjacent in dispatch) beats the half-split by ~13us wall;
// nt beats cached by ~7us within a layout. This round = best of both.
// Per wave: verified R12 ISA load-ring (lane l feeds Gram row l&15, k-group
// l>>4; one half8 is both A and B; mfma(t,t)/(t,r)/(r,r); C/D col=l&15,
// row=kg*4+r). In-block 16-wave LDS reduce + loss; one atomicAdd per block.
// No fences (R14 lesson). VGPR <= 64 (8 waves/SIMD): builds at 52.
__global__ __launch_bounds__(1024)
void ntxent_one(const float* __restrict__ ts0, const float* __restrict__ rs0,
                const float* __restrict__ ts1, const float* __restrict__ rs1,
                const float* __restrict__ ts2, const float* __restrict__ rs2,
                float* __restrict__ out)
{
    __shared__ float red[16][528];
    __shared__ float Gs[16][33];
    __shared__ float rn2[16], tnS[16], rnS[16];

    const int bid  = blockIdx.x;
    const int b    = bid >> 1;
    const int type = bid & 1;

    const int t   = threadIdx.x;
    const int w   = t >> 6;          // wave 0..15
    const int l   = t & 63;
    const int row = l & 15;
    const int kg  = l >> 4;

    float lossTot = 0.f;             // valid at t==0

    if (type == 0) {
        // ---- level 0: D=4096, 256 floats/wave, 8 K-steps, depth-20 ring ----
        const int D = 4096;
        const size_t base = (size_t)b * 16 * D + (size_t)row * D
                          + (size_t)w * 256 + (size_t)kg * 8;
        const float* tsrc = ts0 + base;
        const float* rsrc = rs0 + base;
        f32x4 acc_tt = {0.f, 0.f, 0.f, 0.f};
        f32x4 acc_tr = {0.f, 0.f, 0.f, 0.f};
        f32x4 acc_rr = {0.f, 0.f, 0.f, 0.f};
        ISSUE(g0, 0) ISSUE(g1, 1) ISSUE(g2, 2) ISSUE(g3, 3)
        ISSUE(g4, 4) WAITVM(16); COMPUTE(g0)
        ISSUE(g5, 5) WAITVM(16); COMPUTE(g1)
        ISSUE(g6, 6) WAITVM(16); COMPUTE(g2)
        ISSUE(g7, 7) WAITVM(16); COMPUTE(g3)
        WAITVM(12);  COMPUTE(g4)
        WAITVM(8);   COMPUTE(g5)
        WAITVM(4);   COMPUTE(g6)
        WAITVM(0);   COMPUTE(g7)
        lossTot = reduce_loss(red, Gs, rn2, tnS, rnS, t, w, row, kg,
                              acc_tt, acc_tr, acc_rr);
    } else {
        // ---- level 1: D=2048, 128 floats/wave, 4 K-steps ----
        {
            const int D = 2048;
            const size_t base = (size_t)b * 16 * D + (size_t)row * D
                              + (size_t)w * 128 + (size_t)kg * 8;
            const float* tsrc = ts1 + base;
            const float* rsrc = rs1 + base;
            f32x4 acc_tt = {0.f, 0.f, 0.f, 0.f};
            f32x4 acc_tr = {0.f, 0.f, 0.f, 0.f};
            f32x4 acc_rr = {0.f, 0.f, 0.f, 0.f};
            ISSUE(g0, 0) ISSUE(g1, 1) ISSUE(g2, 2) ISSUE(g3, 3)
            WAITVM(12);  COMPUTE(g0)
            WAITVM(8);   COMPUTE(g1)
            WAITVM(4);   COMPUTE(g2)
            WAITVM(0);   COMPUTE(g3)
            lossTot = reduce_loss(red, Gs, rn2, tnS, rnS, t, w, row, kg,
                                  acc_tt, acc_tr, acc_rr);
        }
        // ---- level 2: D=1024, 64 floats/wave, 2 K-steps ----
        {
            const int D = 1024;
            const size_t base = (size_t)b * 16 * D + (size_t)row * D
                              + (size_t)w * 64 + (size_t)kg * 8;
            const float* tsrc = ts2 + base;
            const float* rsrc = rs2 + base;
            f32x4 acc_tt = {0.f, 0.f, 0.f, 0.f};
            f32x4 acc_tr = {0.f, 0.f, 0.f, 0.f};
            f32x4 acc_rr = {0.f, 0.f, 0.f, 0.f};
            ISSUE(g0, 0) ISSUE(g1, 1)
            WAITVM(4);   COMPUTE(g0)
            WAITVM(0);   COMPUTE(g1)
            lossTot += reduce_loss(red, Gs, rn2, tnS, rnS, t, w, row, kg,
                                   acc_tt, acc_tr, acc_rr);
        }
    }

    if (t == 0) atomicAdd(out, lossTot * (1.0f / 512.0f));
}

extern "C" void kernel_launch(void* const* d_in, const int* in_sizes, int n_in,
                              void* d_out, int out_size, void* d_ws, size_t ws_size,
                              hipStream_t stream) {
    const float* ts0 = (const float*)d_in[0];
    const float* rs0 = (const float*)d_in[1];
    const float* ts1 = (const float*)d_in[2];
    const float* rs1 = (const float*)d_in[3];
    const float* ts2 = (const float*)d_in[4];
    const float* rs2 = (const float*)d_in[5];
    float* out = (float*)d_out;

    hipMemsetAsync(out, 0, sizeof(float), stream);

    const int B = in_sizes[0] / (16 * 4096);   // 256
    hipLaunchKernelGGL(ntxent_one, dim3(B * 2), dim3(1024), 0, stream,
                       ts0, rs0, ts1, rs1, ts2, rs2, out);
}

// Round 20
// 55.002 us; speedup vs baseline: 1.1960x; 1.1044x over previous
//
#include <hip/hip_runtime.h>
#include <math.h>

#define NTX_EPS 1e-8f

typedef __fp16 half8 __attribute__((ext_vector_type(8)));
typedef __fp16 half2v __attribute__((ext_vector_type(2)));
typedef float f32x4 __attribute__((ext_vector_type(4)));

union H8 { half8 v8; half2v v2[4]; };

__device__ __forceinline__ half8 pack8(const float4& a, const float4& b) {
    H8 u;
    u.v2[0] = __builtin_amdgcn_cvt_pkrtz(a.x, a.y);
    u.v2[1] = __builtin_amdgcn_cvt_pkrtz(a.z, a.w);
    u.v2[2] = __builtin_amdgcn_cvt_pkrtz(b.x, b.y);
    u.v2[3] = __builtin_amdgcn_cvt_pkrtz(b.z, b.w);
    return u.v8;
}

// Opaque async load (R12-proven): one global_load_dwordx4 per call; compiler
// cannot recycle destinations into a serialized chain. CACHED (no nt):
// completed 2x2 (R16/R17/R18/R19) shows cached+paired-layout is the best
// cell by ~6-13us wall — same-batch pairs share L2 neighborhoods; nt
// discards that (R19: 52.3 -> 60.7).
__device__ __forceinline__ float4 gl4(const float* p) {
    float4 d;
    asm volatile("global_load_dwordx4 %0, %1, off" : "=v"(d) : "v"(p) : "memory");
    return d;
}
#define WAITVM(n) do { asm volatile("s_waitcnt vmcnt(" #n ")" ::: "memory"); \
                       __builtin_amdgcn_sched_barrier(0); } while (0)

#define ISSUE(g, s) \
    float4 g##T0 = gl4(tsrc + (s) * 32); \
    float4 g##T1 = gl4(tsrc + (s) * 32 + 4); \
    float4 g##R0 = gl4(rsrc + (s) * 32); \
    float4 g##R1 = gl4(rsrc + (s) * 32 + 4);

#define COMPUTE(g) { \
    half8 tf = pack8(g##T0, g##T1); \
    half8 rf = pack8(g##R0, g##R1); \
    acc_tt = __builtin_amdgcn_mfma_f32_16x16x32_f16(tf, tf, acc_tt, 0, 0, 0); \
    acc_tr = __builtin_amdgcn_mfma_f32_16x16x32_f16(tf, rf, acc_tr, 0, 0, 0); \
    acc_rr = __builtin_amdgcn_mfma_f32_16x16x32_f16(rf, rf, acc_rr, 0, 0, 0); }

// Reduce 16 wave-partial Grams in LDS and compute one level's loss.
// Returns the loss (valid at t==0 only). Safe to call twice back-to-back.
__device__ __forceinline__ float reduce_loss(
    float (*red)[528], float (*Gs)[33], float* rn2, float* tnS, float* rnS,
    int t, int w, int row, int kg,
    const f32x4& acc_tt, const f32x4& acc_tr, const f32x4& acc_rr)
{
    const int m = row;
#pragma unroll
    for (int r = 0; r < 4; ++r) {
        const int n = kg * 4 + r;
        red[w][n * 16 + m]       = acc_tt[r];
        red[w][256 + n * 16 + m] = acc_tr[r];
    }
    if ((m >> 2) == kg) red[w][512 + m] = acc_rr[m & 3];
    __syncthreads();

    if (t < 256) {
        float stt = 0.f, str = 0.f;
#pragma unroll
        for (int p = 0; p < 16; ++p) {
            stt += red[p][t];
            str += red[p][256 + t];
        }
        Gs[t >> 4][t & 15]        = stt;
        Gs[t >> 4][16 + (t & 15)] = str;
    } else if (t < 272) {
        const int e = t - 256;
        float s = 0.f;
#pragma unroll
        for (int p = 0; p < 16; ++p) s += red[p][512 + e];
        rn2[e] = s;
    }
    __syncthreads();

    if (t < 16) {
        tnS[t] = fmaxf(sqrtf(Gs[t][t]), NTX_EPS);
        rnS[t] = fmaxf(sqrtf(rn2[t]), NTX_EPS);
    }
    __syncthreads();

    float loss = 0.f;
    if (t < 16) {
        const int n = t;
        const float itn = 2.0f / tnS[n];         // includes 1/temperature
        float lg[32];
#pragma unroll
        for (int j = 0; j < 16; ++j)
            lg[j] = Gs[n][16 + j] * itn / rnS[j];      // s_tr row
#pragma unroll
        for (int k = 0; k < 16; ++k)
            lg[16 + k] = Gs[n][k] * itn / tnS[k];      // s_tt row
        const float pos = lg[n];
        float mx = -3.4e38f;
#pragma unroll
        for (int j = 0; j < 32; ++j)
            mx = (j == 16 + n) ? mx : fmaxf(mx, lg[j]);    // exclude tt diag
        float sm = 0.f;
#pragma unroll
        for (int j = 0; j < 32; ++j)
            sm += (j == 16 + n) ? 0.f : expf(lg[j] - mx);
        loss = logf(sm) + mx - pos;
    }
    loss += __shfl_xor(loss, 1, 64);
    loss += __shfl_xor(loss, 2, 64);
    loss += __shfl_xor(loss, 4, 64);
    loss += __shfl_xor(loss, 8, 64);
    return loss;                                  // valid at t==0
}

// SINGLE kernel: 512 blocks x 1024 threads (16 waves) = exactly 2 blocks/CU.
// Block (b = bid>>1, type = bid&1)  [R16 configuration — best wall 52.3us]:
//   type 0: level 0 of batch b        (512 KB)
//   type 1: levels 1+2 of batch b     (384 KB)
// Per wave: verified R12 ISA load-ring (lane l feeds Gram row l&15, k-group
// l>>4; one half8 is both A and B; mfma(t,t)/(t,r)/(r,r); C/D col=l&15,
// row=kg*4+r). In-block 16-wave LDS reduce + loss; one atomicAdd per block.
// No fences (R14 lesson). VGPR <= 64 (8 waves/SIMD): builds at 52.
__global__ __launch_bounds__(1024)
void ntxent_one(const float* __restrict__ ts0, const float* __restrict__ rs0,
                const float* __restrict__ ts1, const float* __restrict__ rs1,
                const float* __restrict__ ts2, const float* __restrict__ rs2,
                float* __restrict__ out)
{
    __shared__ float red[16][528];
    __shared__ float Gs[16][33];
    __shared__ float rn2[16], tnS[16], rnS[16];

    const int bid  = blockIdx.x;
    const int b    = bid >> 1;
    const int type = bid & 1;

    const int t   = threadIdx.x;
    const int w   = t >> 6;          // wave 0..15
    const int l   = t & 63;
    const int row = l & 15;
    const int kg  = l >> 4;

    float lossTot = 0.f;             // valid at t==0

    if (type == 0) {
        // ---- level 0: D=4096, 256 floats/wave, 8 K-steps, depth-20 ring ----
        const int D = 4096;
        const size_t base = (size_t)b * 16 * D + (size_t)row * D
                          + (size_t)w * 256 + (size_t)kg * 8;
        const float* tsrc = ts0 + base;
        const float* rsrc = rs0 + base;
        f32x4 acc_tt = {0.f, 0.f, 0.f, 0.f};
        f32x4 acc_tr = {0.f, 0.f, 0.f, 0.f};
        f32x4 acc_rr = {0.f, 0.f, 0.f, 0.f};
        ISSUE(g0, 0) ISSUE(g1, 1) ISSUE(g2, 2) ISSUE(g3, 3)
        ISSUE(g4, 4) WAITVM(16); COMPUTE(g0)
        ISSUE(g5, 5) WAITVM(16); COMPUTE(g1)
        ISSUE(g6, 6) WAITVM(16); COMPUTE(g2)
        ISSUE(g7, 7) WAITVM(16); COMPUTE(g3)
        WAITVM(12);  COMPUTE(g4)
        WAITVM(8);   COMPUTE(g5)
        WAITVM(4);   COMPUTE(g6)
        WAITVM(0);   COMPUTE(g7)
        lossTot = reduce_loss(red, Gs, rn2, tnS, rnS, t, w, row, kg,
                              acc_tt, acc_tr, acc_rr);
    } else {
        // ---- level 1: D=2048, 128 floats/wave, 4 K-steps ----
        {
            const int D = 2048;
            const size_t base = (size_t)b * 16 * D + (size_t)row * D
                              + (size_t)w * 128 + (size_t)kg * 8;
            const float* tsrc = ts1 + base;
            const float* rsrc = rs1 + base;
            f32x4 acc_tt = {0.f, 0.f, 0.f, 0.f};
            f32x4 acc_tr = {0.f, 0.f, 0.f, 0.f};
            f32x4 acc_rr = {0.f, 0.f, 0.f, 0.f};
            ISSUE(g0, 0) ISSUE(g1, 1) ISSUE(g2, 2) ISSUE(g3, 3)
            WAITVM(12);  COMPUTE(g0)
            WAITVM(8);   COMPUTE(g1)
            WAITVM(4);   COMPUTE(g2)
            WAITVM(0);   COMPUTE(g3)
            lossTot = reduce_loss(red, Gs, rn2, tnS, rnS, t, w, row, kg,
                                  acc_tt, acc_tr, acc_rr);
        }
        // ---- level 2: D=1024, 64 floats/wave, 2 K-steps ----
        {
            const int D = 1024;
            const size_t base = (size_t)b * 16 * D + (size_t)row * D
                              + (size_t)w * 64 + (size_t)kg * 8;
            const float* tsrc = ts2 + base;
            const float* rsrc = rs2 + base;
            f32x4 acc_tt = {0.f, 0.f, 0.f, 0.f};
            f32x4 acc_tr = {0.f, 0.f, 0.f, 0.f};
            f32x4 acc_rr = {0.f, 0.f, 0.f, 0.f};
            ISSUE(g0, 0) ISSUE(g1, 1)
            WAITVM(4);   COMPUTE(g0)
            WAITVM(0);   COMPUTE(g1)
            lossTot += reduce_loss(red, Gs, rn2, tnS, rnS, t, w, row, kg,
                                   acc_tt, acc_tr, acc_rr);
        }
    }

    if (t == 0) atomicAdd(out, lossTot * (1.0f / 512.0f));
}

extern "C" void kernel_launch(void* const* d_in, const int* in_sizes, int n_in,
                              void* d_out, int out_size, void* d_ws, size_t ws_size,
                              hipStream_t stream) {
    const float* ts0 = (const float*)d_in[0];
    const float* rs0 = (const float*)d_in[1];
    const float* ts1 = (const float*)d_in[2];
    const float* rs1 = (const float*)d_in[3];
    const float* ts2 = (const float*)d_in[4];
    const float* rs2 = (const float*)d_in[5];
    float* out = (float*)d_out;

    hipMemsetAsync(out, 0, sizeof(float), stream);

    const int B = in_sizes[0] / (16 * 4096);   // 256
    hipLaunchKernelGGL(ntxent_one, dim3(B * 2), dim3(1024), 0, stream,
                       ts0, rs0, ts1, rs1, ts2, rs2, out);
}

// Round 21
// 54.825 us; speedup vs baseline: 1.1999x; 1.0032x over previous
//
#include <hip/hip_runtime.h>
#include <math.h>

#define NTX_EPS 1e-8f

typedef __fp16 half8 __attribute__((ext_vector_type(8)));
typedef __fp16 half2v __attribute__((ext_vector_type(2)));
typedef float f32x4 __attribute__((ext_vector_type(4)));

union H8 { half8 v8; half2v v2[4]; };

__device__ __forceinline__ half8 pack8(const float4& a, const float4& b) {
    H8 u;
    u.v2[0] = __builtin_amdgcn_cvt_pkrtz(a.x, a.y);
    u.v2[1] = __builtin_amdgcn_cvt_pkrtz(a.z, a.w);
    u.v2[2] = __builtin_amdgcn_cvt_pkrtz(b.x, b.y);
    u.v2[3] = __builtin_amdgcn_cvt_pkrtz(b.z, b.w);
    return u.v8;
}

// Opaque async load (R12-proven): one global_load_dwordx4 per call; compiler
// cannot recycle destinations into a serialized chain. CACHED (no nt): nt
// defeats L3 residency across graph replays (R19: 52.3 -> 60.7 wall).
__device__ __forceinline__ float4 gl4(const float* p) {
    float4 d;
    asm volatile("global_load_dwordx4 %0, %1, off" : "=v"(d) : "v"(p) : "memory");
    return d;
}
#define WAITVM(n) do { asm volatile("s_waitcnt vmcnt(" #n ")" ::: "memory"); \
                       __builtin_amdgcn_sched_barrier(0); } while (0)

#define ISSUE(g, s) \
    float4 g##T0 = gl4(tsrc + (s) * 32); \
    float4 g##T1 = gl4(tsrc + (s) * 32 + 4); \
    float4 g##R0 = gl4(rsrc + (s) * 32); \
    float4 g##R1 = gl4(rsrc + (s) * 32 + 4);

#define COMPUTE(g) { \
    half8 tf = pack8(g##T0, g##T1); \
    half8 rf = pack8(g##R0, g##R1); \
    acc_tt = __builtin_amdgcn_mfma_f32_16x16x32_f16(tf, tf, acc_tt, 0, 0, 0); \
    acc_tr = __builtin_amdgcn_mfma_f32_16x16x32_f16(tf, rf, acc_tr, 0, 0, 0); \
    acc_rr = __builtin_amdgcn_mfma_f32_16x16x32_f16(rf, rf, acc_rr, 0, 0, 0); }

// Reduce 16 wave-partial Grams in LDS and compute one level's loss.
// Returns the loss (valid at t==0 only). Safe to call twice back-to-back.
__device__ __forceinline__ float reduce_loss(
    float (*red)[528], float (*Gs)[33], float* rn2, float* tnS, float* rnS,
    int t, int w, int row, int kg,
    const f32x4& acc_tt, const f32x4& acc_tr, const f32x4& acc_rr)
{
    const int m = row;
#pragma unroll
    for (int r = 0; r < 4; ++r) {
        const int n = kg * 4 + r;
        red[w][n * 16 + m]       = acc_tt[r];
        red[w][256 + n * 16 + m] = acc_tr[r];
    }
    if ((m >> 2) == kg) red[w][512 + m] = acc_rr[m & 3];
    __syncthreads();

    if (t < 256) {
        float stt = 0.f, str = 0.f;
#pragma unroll
        for (int p = 0; p < 16; ++p) {
            stt += red[p][t];
            str += red[p][256 + t];
        }
        Gs[t >> 4][t & 15]        = stt;
        Gs[t >> 4][16 + (t & 15)] = str;
    } else if (t < 272) {
        const int e = t - 256;
        float s = 0.f;
#pragma unroll
        for (int p = 0; p < 16; ++p) s += red[p][512 + e];
        rn2[e] = s;
    }
    __syncthreads();

    if (t < 16) {
        tnS[t] = fmaxf(sqrtf(Gs[t][t]), NTX_EPS);
        rnS[t] = fmaxf(sqrtf(rn2[t]), NTX_EPS);
    }
    __syncthreads();

    float loss = 0.f;
    if (t < 16) {
        const int n = t;
        const float itn = 2.0f / tnS[n];         // includes 1/temperature
        float lg[32];
#pragma unroll
        for (int j = 0; j < 16; ++j)
            lg[j] = Gs[n][16 + j] * itn / rnS[j];      // s_tr row
#pragma unroll
        for (int k = 0; k < 16; ++k)
            lg[16 + k] = Gs[n][k] * itn / tnS[k];      // s_tt row
        const float pos = lg[n];
        float mx = -3.4e38f;
#pragma unroll
        for (int j = 0; j < 32; ++j)
            mx = (j == 16 + n) ? mx : fmaxf(mx, lg[j]);    // exclude tt diag
        float sm = 0.f;
#pragma unroll
        for (int j = 0; j < 32; ++j)
            sm += (j == 16 + n) ? 0.f : expf(lg[j] - mx);
        loss = logf(sm) + mx - pos;
    }
    loss += __shfl_xor(loss, 1, 64);
    loss += __shfl_xor(loss, 2, 64);
    loss += __shfl_xor(loss, 4, 64);
    loss += __shfl_xor(loss, 8, 64);
    return loss;                                  // valid at t==0
}

// SINGLE kernel: 512 blocks x 1024 threads (16 waves) = exactly 2 blocks/CU.
// R21 mapping (XCD-balanced + CU-homogeneous; single change vs R20):
//   x = bid&7 (XCD via round-robin), j = bid>>3, type = j&1,
//   b = x*32 + (j>>1).
// Dispatch arithmetic: CU c of XCD x receives blocks with j=c and j=32+c ->
// SAME type on both (32 even); each XCD gets 16 heavy-CUs (2x512KB) + 16
// light-CUs (2x384KB) = 28 MB/XCD, exactly balanced (R16/R20's type=bid&1
// gave even XCDs 32 MB, odd 24 MB). Both blocks of batch b share XCD x.
//   type 0: level 0 of batch b        (512 KB)
//   type 1: levels 1+2 of batch b     (384 KB)
// Per wave: verified R12 ISA load-ring (lane l feeds Gram row l&15, k-group
// l>>4; one half8 is both A and B; mfma(t,t)/(t,r)/(r,r); C/D col=l&15,
// row=kg*4+r). In-block 16-wave LDS reduce + loss; one atomicAdd per block.
// No fences (R14 lesson). VGPR <= 64 (8 waves/SIMD): builds at 52.
__global__ __launch_bounds__(1024)
void ntxent_one(const float* __restrict__ ts0, const float* __restrict__ rs0,
                const float* __restrict__ ts1, const float* __restrict__ rs1,
                const float* __restrict__ ts2, const float* __restrict__ rs2,
                float* __restrict__ out)
{
    __shared__ float red[16][528];
    __shared__ float Gs[16][33];
    __shared__ float rn2[16], tnS[16], rnS[16];

    const int bid  = blockIdx.x;
    const int x    = bid & 7;
    const int j    = bid >> 3;
    const int type = j & 1;
    const int b    = x * 32 + (j >> 1);

    const int t   = threadIdx.x;
    const int w   = t >> 6;          // wave 0..15
    const int l   = t & 63;
    const int row = l & 15;
    const int kg  = l >> 4;

    float lossTot = 0.f;             // valid at t==0

    if (type == 0) {
        // ---- level 0: D=4096, 256 floats/wave, 8 K-steps, depth-20 ring ----
        const int D = 4096;
        const size_t base = (size_t)b * 16 * D + (size_t)row * D
                          + (size_t)w * 256 + (size_t)kg * 8;
        const float* tsrc = ts0 + base;
        const float* rsrc = rs0 + base;
        f32x4 acc_tt = {0.f, 0.f, 0.f, 0.f};
        f32x4 acc_tr = {0.f, 0.f, 0.f, 0.f};
        f32x4 acc_rr = {0.f, 0.f, 0.f, 0.f};
        ISSUE(g0, 0) ISSUE(g1, 1) ISSUE(g2, 2) ISSUE(g3, 3)
        ISSUE(g4, 4) WAITVM(16); COMPUTE(g0)
        ISSUE(g5, 5) WAITVM(16); COMPUTE(g1)
        ISSUE(g6, 6) WAITVM(16); COMPUTE(g2)
        ISSUE(g7, 7) WAITVM(16); COMPUTE(g3)
        WAITVM(12);  COMPUTE(g4)
        WAITVM(8);   COMPUTE(g5)
        WAITVM(4);   COMPUTE(g6)
        WAITVM(0);   COMPUTE(g7)
        lossTot = reduce_loss(red, Gs, rn2, tnS, rnS, t, w, row, kg,
                              acc_tt, acc_tr, acc_rr);
    } else {
        // ---- level 1: D=2048, 128 floats/wave, 4 K-steps ----
        {
            const int D = 2048;
            const size_t base = (size_t)b * 16 * D + (size_t)row * D
                              + (size_t)w * 128 + (size_t)kg * 8;
            const float* tsrc = ts1 + base;
            const float* rsrc = rs1 + base;
            f32x4 acc_tt = {0.f, 0.f, 0.f, 0.f};
            f32x4 acc_tr = {0.f, 0.f, 0.f, 0.f};
            f32x4 acc_rr = {0.f, 0.f, 0.f, 0.f};
            ISSUE(g0, 0) ISSUE(g1, 1) ISSUE(g2, 2) ISSUE(g3, 3)
            WAITVM(12);  COMPUTE(g0)
            WAITVM(8);   COMPUTE(g1)
            WAITVM(4);   COMPUTE(g2)
            WAITVM(0);   COMPUTE(g3)
            lossTot = reduce_loss(red, Gs, rn2, tnS, rnS, t, w, row, kg,
                                  acc_tt, acc_tr, acc_rr);
        }
        // ---- level 2: D=1024, 64 floats/wave, 2 K-steps ----
        {
            const int D = 1024;
            const size_t base = (size_t)b * 16 * D + (size_t)row * D
                              + (size_t)w * 64 + (size_t)kg * 8;
            const float* tsrc = ts2 + base;
            const float* rsrc = rs2 + base;
            f32x4 acc_tt = {0.f, 0.f, 0.f, 0.f};
            f32x4 acc_tr = {0.f, 0.f, 0.f, 0.f};
            f32x4 acc_rr = {0.f, 0.f, 0.f, 0.f};
            ISSUE(g0, 0) ISSUE(g1, 1)
            WAITVM(4);   COMPUTE(g0)
            WAITVM(0);   COMPUTE(g1)
            lossTot += reduce_loss(red, Gs, rn2, tnS, rnS, t, w, row, kg,
                                   acc_tt, acc_tr, acc_rr);
        }
    }

    if (t == 0) atomicAdd(out, lossTot * (1.0f / 512.0f));
}

extern "C" void kernel_launch(void* const* d_in, const int* in_sizes, int n_in,
                              void* d_out, int out_size, void* d_ws, size_t ws_size,
                              hipStream_t stream) {
    const float* ts0 = (const float*)d_in[0];
    const float* rs0 = (const float*)d_in[1];
    const float* ts1 = (const float*)d_in[2];
    const float* rs1 = (const float*)d_in[3];
    const float* ts2 = (const float*)d_in[4];
    const float* rs2 = (const float*)d_in[5];
    float* out = (float*)d_out;

    hipMemsetAsync(out, 0, sizeof(float), stream);

    const int B = in_sizes[0] / (16 * 4096);   // 256
    hipLaunchKernelGGL(ntxent_one, dim3(B * 2), dim3(1024), 0, stream,
                       ts0, rs0, ts1, rs1, ts2, rs2, out);
}